// Round 9
// baseline (158.388 us; speedup 1.0000x reference)
//
#include <hip/hip_runtime.h>
#include <hip/hip_bf16.h>

typedef __attribute__((ext_vector_type(8))) short short8;
typedef __attribute__((ext_vector_type(4))) float f32x4;

#define NROW 8192
#define DIM 512
#define BHALF 4096
#define NB 64            // number of 128-row blocks
#define BM 128
#define NPAIR 2080       // NB*(NB+1)/2
#define XCHUNK 260       // 2080/8

// ---------------- Kernel 1: row L2-normalize fp32 -> bf16 (wave per row) ----------------
__global__ __launch_bounds__(256) void normalize_kernel(const float* __restrict__ in,
                                                        __hip_bfloat16* __restrict__ out) {
  const int w = threadIdx.x >> 6, lane = threadIdx.x & 63;
  const int row = blockIdx.x * 4 + w;
  const float4* src = (const float4*)(in + (size_t)row * DIM) + lane * 2;
  const float4 v0 = src[0], v1 = src[1];
  float ss = v0.x * v0.x + v0.y * v0.y + v0.z * v0.z + v0.w * v0.w
           + v1.x * v1.x + v1.y * v1.y + v1.z * v1.z + v1.w * v1.w;
  #pragma unroll
  for (int m = 1; m < 64; m <<= 1) ss += __shfl_xor(ss, m);
  const float inv = 1.0f / fmaxf(sqrtf(ss), 1e-12f);
  __hip_bfloat16 o[8];
  o[0] = __float2bfloat16(v0.x * inv); o[1] = __float2bfloat16(v0.y * inv);
  o[2] = __float2bfloat16(v0.z * inv); o[3] = __float2bfloat16(v0.w * inv);
  o[4] = __float2bfloat16(v1.x * inv); o[5] = __float2bfloat16(v1.y * inv);
  o[6] = __float2bfloat16(v1.z * inv); o[7] = __float2bfloat16(v1.w * inv);
  *(short8*)(out + (size_t)row * DIM + lane * 8) = *(const short8*)o;
}

// ---------------- Kernel 2: symmetric 128x128 pair-tile Gram, NO-LDS main loop ----------------
// 2080 blocks (ib<=jb pairs), 256 threads = 4 waves (2x2), 4x4 frags of 16x16x32.
// MFMA fragments are loaded DIRECTLY from global (L1/L2-resident f): lane fr
// reads 16B of row base+fr at k-offset g*8 -> one global_load_dwordx4 per frag,
// dense 16x64B segments per wave. No LDS staging, no barriers in the K-loop;
// latency hidden by a 2-deep named-buffer register pipeline + 3 blocks/CU.
// Macro 16x16 pair-locality + bijective XCD swizzle keep panels L2-resident.
__global__ __launch_bounds__(256, 3) void pair_gram_kernel(const __hip_bfloat16* __restrict__ f,
                                                           float* __restrict__ psum,
                                                           float* __restrict__ ppos) {
  __shared__ float sc[1024];   // epilogue cross-wave reduce only (4 KB)

  // --- XCD swizzle + 16x16 macro-tiled triangular pair decode (scalar-uniform) ---
  const int bid = blockIdx.x;
  const int wg = (bid & 7) * XCHUNK + (bid >> 3);
  int rem = wg, MI = 0, MJ = 0;
  {
    bool brk = false;
    for (MI = 0; MI < 4 && !brk; ++MI) {
      for (MJ = MI; MJ < 4; ++MJ) {
        const int sz = (MI == MJ) ? 136 : 256;
        if (rem < sz) { brk = true; break; }
        rem -= sz;
      }
    }
    if (brk) --MI;
  }
  int ib, jb;
  if (MI == MJ) {          // 16x16 triangle: 136 entries
    int i = 0, b = 0;
    while (b + (16 - i) <= rem) { b += 16 - i; ++i; }
    ib = MI * 16 + i; jb = MI * 16 + i + (rem - b);
  } else {
    ib = MI * 16 + (rem >> 4); jb = MJ * 16 + (rem & 15);
  }

  const int tid = threadIdx.x;
  const int lane = tid & 63;
  const int w = tid >> 6;            // wave 0..3
  const int wy = w >> 1;             // row half (0/1): rows wy*64..+64
  const int wx = w & 1;              // col half (0/1): cols wx*64..+64
  const int fr = lane & 15;          // fragment row/col index
  const int g = lane >> 4;           // k-group / C-row group

  // per-lane fragment base pointers (k-step offset kt*32 elems = kt*64 B folds
  // into the 13-bit signed global_load offset immediate)
  const __hip_bfloat16* pA0 = f + (size_t)(ib * BM + wy * 64 + 0 * 16 + fr) * DIM + g * 8;
  const __hip_bfloat16* pA1 = pA0 + (size_t)16 * DIM;
  const __hip_bfloat16* pA2 = pA0 + (size_t)32 * DIM;
  const __hip_bfloat16* pA3 = pA0 + (size_t)48 * DIM;
  const __hip_bfloat16* pB0 = f + (size_t)(jb * BM + wx * 64 + 0 * 16 + fr) * DIM + g * 8;
  const __hip_bfloat16* pB1 = pB0 + (size_t)16 * DIM;
  const __hip_bfloat16* pB2 = pB0 + (size_t)32 * DIM;
  const __hip_bfloat16* pB3 = pB0 + (size_t)48 * DIM;

  f32x4 acc[4][4];
  const f32x4 zero = {0.f, 0.f, 0.f, 0.f};
  #pragma unroll
  for (int mi = 0; mi < 4; ++mi)
    #pragma unroll
    for (int ni = 0; ni < 4; ++ni) acc[mi][ni] = zero;

  #define LOADF(A, B, kt)                               \
    A[0] = *(const short8*)(pA0 + (kt) * 32);           \
    A[1] = *(const short8*)(pA1 + (kt) * 32);           \
    A[2] = *(const short8*)(pA2 + (kt) * 32);           \
    A[3] = *(const short8*)(pA3 + (kt) * 32);           \
    B[0] = *(const short8*)(pB0 + (kt) * 32);           \
    B[1] = *(const short8*)(pB1 + (kt) * 32);           \
    B[2] = *(const short8*)(pB2 + (kt) * 32);           \
    B[3] = *(const short8*)(pB3 + (kt) * 32);

  #define MFMAQ(A, B)                                                              \
    _Pragma("unroll") for (int mi = 0; mi < 4; ++mi)                               \
    _Pragma("unroll") for (int ni = 0; ni < 4; ++ni)                               \
      acc[mi][ni] = __builtin_amdgcn_mfma_f32_16x16x32_bf16(A[mi], B[ni], acc[mi][ni], 0, 0, 0);

  // 2-deep register pipeline, named even/odd buffers (static indexing)
  short8 aX[4], bX[4], aY[4], bY[4];
  LOADF(aX, bX, 0);
  #pragma unroll
  for (int t = 0; t < 16; t += 2) {
    if (t + 1 < 16) { LOADF(aY, bY, t + 1); }
    MFMAQ(aX, bX);
    if (t + 2 < 16) { LOADF(aX, bX, t + 2); }
    MFMAQ(aY, bY);
  }
  #undef LOADF
  #undef MFMAQ

  // ---- epilogue: exp, row-sums (rows of ib) + col-sums (rows of jb), pos-pair ----
  float rsum[4][4], prow[4][4], csum[4], pcol[4];
  #pragma unroll
  for (int mi = 0; mi < 4; ++mi)
    #pragma unroll
    for (int r = 0; r < 4; ++r) { rsum[mi][r] = 0.f; prow[mi][r] = 0.f; }
  #pragma unroll
  for (int ni = 0; ni < 4; ++ni) { csum[ni] = 0.f; pcol[ni] = 0.f; }

  #pragma unroll
  for (int mi = 0; mi < 4; ++mi) {
    #pragma unroll
    for (int ni = 0; ni < 4; ++ni) {
      const int gcol = jb * BM + wx * 64 + ni * 16 + fr;
      #pragma unroll
      for (int r = 0; r < 4; ++r) {
        const int grow = ib * BM + wy * 64 + mi * 16 + g * 4 + r;
        const float dot = acc[mi][ni][r];
        const float e = (gcol == grow) ? 0.f : __expf((dot - 1.0f) * 10.0f);
        const float pos = (gcol == (grow ^ BHALF)) ? dot : 0.f;
        rsum[mi][r] += e;  prow[mi][r] += pos;
        csum[ni] += e;     pcol[ni] += pos;
      }
    }
  }

  // row side: reduce over fr (lane bits 0..3)
  #pragma unroll
  for (int mi = 0; mi < 4; ++mi)
    #pragma unroll
    for (int r = 0; r < 4; ++r) {
      float a = rsum[mi][r], b = prow[mi][r];
      #pragma unroll
      for (int msk = 1; msk < 16; msk <<= 1) { a += __shfl_xor(a, msk); b += __shfl_xor(b, msk); }
      rsum[mi][r] = a; prow[mi][r] = b;
    }
  // col side: reduce over g (lane bits 4..5)
  #pragma unroll
  for (int ni = 0; ni < 4; ++ni) {
    float a = csum[ni], b = pcol[ni];
    a += __shfl_xor(a, 16); b += __shfl_xor(b, 16);
    a += __shfl_xor(a, 32); b += __shfl_xor(b, 32);
    csum[ni] = a; pcol[ni] = b;
  }

  // cross-wave combine: rS[wx][128]@0, rP@256, cS[wy][128]@512, cP@768
  if (fr == 0) {
    #pragma unroll
    for (int mi = 0; mi < 4; ++mi)
      #pragma unroll
      for (int r = 0; r < 4; ++r) {
        const int row = wy * 64 + mi * 16 + g * 4 + r;
        sc[wx * 128 + row]       = rsum[mi][r];
        sc[256 + wx * 128 + row] = prow[mi][r];
      }
  }
  if (g == 0) {
    #pragma unroll
    for (int ni = 0; ni < 4; ++ni) {
      const int col = wx * 64 + ni * 16 + fr;
      sc[512 + wy * 128 + col] = csum[ni];
      sc[768 + wy * 128 + col] = pcol[ni];
    }
  }
  __syncthreads();

  if (tid < 128) {                     // rows of block ib -> slot jb
    const int row = tid;
    const float s = sc[row] + sc[128 + row];
    const float p = sc[256 + row] + sc[384 + row];
    psum[(size_t)jb * NROW + ib * BM + row] = s;
    ppos[(size_t)jb * NROW + ib * BM + row] = p;
  } else if (ib != jb) {               // rows of block jb -> slot ib (transpose side)
    const int col = tid - 128;
    const float s = sc[512 + col] + sc[640 + col];
    const float p = sc[768 + col] + sc[896 + col];
    psum[(size_t)ib * NROW + jb * BM + col] = s;
    ppos[(size_t)ib * NROW + jb * BM + col] = p;
  }
}

// ---------------- Kernel 3a: per-row loss, 64 partials ----------------
__global__ __launch_bounds__(128) void loss_stage1(const float* __restrict__ psum,
                                                   const float* __restrict__ ppos,
                                                   float* __restrict__ partial) {
  const int row = blockIdx.x * 128 + threadIdx.x;
  float s = 0.f, p = 0.f;
  #pragma unroll 8
  for (int sl = 0; sl < NB; ++sl) {
    s += psum[(size_t)sl * NROW + row];
    p += ppos[(size_t)sl * NROW + row];
  }
  float local = logf(s) + 10.0f - 10.0f * p;
  #pragma unroll
  for (int m = 1; m < 64; m <<= 1) local += __shfl_xor(local, m);
  __shared__ float red[2];
  if ((threadIdx.x & 63) == 0) red[threadIdx.x >> 6] = local;
  __syncthreads();
  if (threadIdx.x == 0) partial[blockIdx.x] = red[0] + red[1];
}

// ---------------- Kernel 3b: final scalar ----------------
__global__ __launch_bounds__(64) void loss_stage2(const float* __restrict__ partial,
                                                  float* __restrict__ out) {
  float v = partial[threadIdx.x];
  #pragma unroll
  for (int m = 1; m < 64; m <<= 1) v += __shfl_xor(v, m);
  if (threadIdx.x == 0) out[0] = v * (1.0f / (float)BHALF);
}

extern "C" void kernel_launch(void* const* d_in, const int* in_sizes, int n_in,
                              void* d_out, int out_size, void* d_ws, size_t ws_size,
                              hipStream_t stream) {
  const float* feat = (const float*)d_in[0];
  char* ws = (char*)d_ws;
  __hip_bfloat16* f = (__hip_bfloat16*)ws;                         // 8 MB
  float* psum = (float*)(ws + (size_t)NROW * DIM * 2);             // NB*NROW floats (2 MB)
  float* ppos = psum + (size_t)NB * NROW;                          // 2 MB
  float* partial = ppos + (size_t)NB * NROW;                       // 64 floats
  float* out = (float*)d_out;

  normalize_kernel<<<NROW / 4, 256, 0, stream>>>(feat, f);
  pair_gram_kernel<<<NPAIR, 256, 0, stream>>>(f, psum, ppos);
  loss_stage1<<<NROW / 128, 128, 0, stream>>>(psum, ppos, partial);
  loss_stage2<<<1, 64, 0, stream>>>(partial, out);
}

// Round 10
// 71.651 us; speedup vs baseline: 2.2106x; 2.2106x over previous
//
#include <hip/hip_runtime.h>
#include <hip/hip_bf16.h>

typedef __attribute__((ext_vector_type(8))) short short8;
typedef __attribute__((ext_vector_type(4))) float f32x4;

#define NROW 8192
#define DIM 512
#define BHALF 4096
#define NB 64            // number of 128-row blocks
#define BM 128
#define BK 64            // 128-B LDS rows + XOR swizzle -> measured 0 bank conflicts
#define NPAIR 2080       // NB*(NB+1)/2
#define XCHUNK 260       // 2080/8

__device__ __forceinline__ void gload_lds16(const void* g, void* l) {
  __builtin_amdgcn_global_load_lds(
      (const __attribute__((address_space(1))) void*)g,
      (__attribute__((address_space(3))) void*)l,
      16, 0, 0);
}

// ---------------- Kernel 1: row L2-normalize fp32 -> bf16 (wave per row) ----------------
__global__ __launch_bounds__(256) void normalize_kernel(const float* __restrict__ in,
                                                        __hip_bfloat16* __restrict__ out) {
  const int w = threadIdx.x >> 6, lane = threadIdx.x & 63;
  const int row = blockIdx.x * 4 + w;
  const float4* src = (const float4*)(in + (size_t)row * DIM) + lane * 2;
  const float4 v0 = src[0], v1 = src[1];
  float ss = v0.x * v0.x + v0.y * v0.y + v0.z * v0.z + v0.w * v0.w
           + v1.x * v1.x + v1.y * v1.y + v1.z * v1.z + v1.w * v1.w;
  #pragma unroll
  for (int m = 1; m < 64; m <<= 1) ss += __shfl_xor(ss, m);
  const float inv = 1.0f / fmaxf(sqrtf(ss), 1e-12f);
  __hip_bfloat16 o[8];
  o[0] = __float2bfloat16(v0.x * inv); o[1] = __float2bfloat16(v0.y * inv);
  o[2] = __float2bfloat16(v0.z * inv); o[3] = __float2bfloat16(v0.w * inv);
  o[4] = __float2bfloat16(v1.x * inv); o[5] = __float2bfloat16(v1.y * inv);
  o[6] = __float2bfloat16(v1.z * inv); o[7] = __float2bfloat16(v1.w * inv);
  *(short8*)(out + (size_t)row * DIM + lane * 8) = *(const short8*)o;
}

// ---------------- Kernel 2: symmetric 128x128 pair-tile Gram + exp-sums ----------------
// r7 structure (best measured: 57.9us): 2080 blocks (ib<=jb pairs), 256 threads
// = 4 waves (2x2), 4x4 frags of 16x16x32. BK=64, SINGLE-buffer 32 KB LDS,
// 2-barrier K-loop. XOR swizzle (proven 0 conflicts). ONE change vs r7:
// __launch_bounds__(256,4) -> allocator fits 4 waves/EU (<=128 unified
// VGPR+AGPR) -> 4 blocks/CU co-resident instead of 3 (more drain hiding).
__global__ __launch_bounds__(256, 4) void pair_gram_kernel(const __hip_bfloat16* __restrict__ f,
                                                           float* __restrict__ psum,
                                                           float* __restrict__ ppos) {
  __shared__ __align__(16) char lds[32768];   // A[128][64] @0, B[128][64] @16384

  // --- XCD swizzle + 16x16 macro-tiled triangular pair decode (scalar-uniform) ---
  const int bid = blockIdx.x;
  const int wg = (bid & 7) * XCHUNK + (bid >> 3);
  int rem = wg, MI = 0, MJ = 0;
  {
    bool brk = false;
    for (MI = 0; MI < 4 && !brk; ++MI) {
      for (MJ = MI; MJ < 4; ++MJ) {
        const int sz = (MI == MJ) ? 136 : 256;
        if (rem < sz) { brk = true; break; }
        rem -= sz;
      }
    }
    if (brk) --MI;
  }
  int ib, jb;
  if (MI == MJ) {          // 16x16 triangle: 136 entries
    int i = 0, b = 0;
    while (b + (16 - i) <= rem) { b += 16 - i; ++i; }
    ib = MI * 16 + i; jb = MI * 16 + i + (rem - b);
  } else {
    ib = MI * 16 + (rem >> 4); jb = MJ * 16 + (rem & 15);
  }

  const int tid = threadIdx.x;
  const int lane = tid & 63;
  const int w = tid >> 6;            // wave 0..3
  const int wy = w >> 1;             // row half (0/1): rows wy*64..+64
  const int wx = w & 1;              // col half (0/1): cols wx*64..+64
  const int fr = lane & 15;          // fragment row/col index
  const int g = lane >> 4;           // k-group / C-row group

  // staging source (inverse-swizzled): lane covers row w*8+(lane>>3) (+q*32),
  // global col16 (lane&7)^((lane>>3)&7); LDS dest linear (base + lane*16).
  const int srow8 = lane >> 3;
  const int scol = (lane & 7) ^ srow8;
  const __hip_bfloat16* gA = f + (size_t)(ib * BM + w * 8 + srow8) * DIM + scol * 8;
  const __hip_bfloat16* gB = f + (size_t)(jb * BM + w * 8 + srow8) * DIM + scol * 8;
  char* dA = lds + w * 1024;          // + q*4096
  char* dB = lds + 16384 + w * 1024;  // + q*4096

  f32x4 acc[4][4];
  const f32x4 zero = {0.f, 0.f, 0.f, 0.f};
  #pragma unroll
  for (int mi = 0; mi < 4; ++mi)
    #pragma unroll
    for (int ni = 0; ni < 4; ++ni) acc[mi][ni] = zero;

  // read-side swizzled 16B-slot offsets: sk(kk) = ((kk*4+g) ^ (fr&7)) * 16
  const int f7 = fr & 7;
  const int sk0 = ((0 + g) ^ f7) * 16;
  const int sk1 = ((4 + g) ^ f7) * 16;
  const int arow = (wy * 64 + fr) * 128;          // + mi*16*128
  const int brow = 16384 + (wx * 64 + fr) * 128;  // + ni*16*128

  for (int t = 0; t < 8; ++t) {
    __syncthreads();                  // previous tile's ds_reads complete
    const int k0 = t * BK;
    #pragma unroll
    for (int q = 0; q < 4; ++q) {
      gload_lds16(gA + k0 + (size_t)q * 32 * DIM, dA + q * 4096);
      gload_lds16(gB + k0 + (size_t)q * 32 * DIM, dB + q * 4096);
    }
    __syncthreads();                  // vmcnt(0) drain: tile staged

    #pragma unroll
    for (int kk = 0; kk < 2; ++kk) {
      const int sk = kk ? sk1 : sk0;
      short8 aF[4], bF[4];
      #pragma unroll
      for (int mi = 0; mi < 4; ++mi) aF[mi] = *(const short8*)(lds + arow + mi * 2048 + sk);
      #pragma unroll
      for (int ni = 0; ni < 4; ++ni) bF[ni] = *(const short8*)(lds + brow + ni * 2048 + sk);
      __builtin_amdgcn_s_setprio(1);
      #pragma unroll
      for (int mi = 0; mi < 4; ++mi)
        #pragma unroll
        for (int ni = 0; ni < 4; ++ni)
          acc[mi][ni] = __builtin_amdgcn_mfma_f32_16x16x32_bf16(aF[mi], bF[ni], acc[mi][ni], 0, 0, 0);
      __builtin_amdgcn_s_setprio(0);
    }
  }

  // ---- epilogue: exp, row-sums (rows of ib) + col-sums (rows of jb), pos-pair ----
  float rsum[4][4], prow[4][4], csum[4], pcol[4];
  #pragma unroll
  for (int mi = 0; mi < 4; ++mi)
    #pragma unroll
    for (int r = 0; r < 4; ++r) { rsum[mi][r] = 0.f; prow[mi][r] = 0.f; }
  #pragma unroll
  for (int ni = 0; ni < 4; ++ni) { csum[ni] = 0.f; pcol[ni] = 0.f; }

  #pragma unroll
  for (int mi = 0; mi < 4; ++mi) {
    #pragma unroll
    for (int ni = 0; ni < 4; ++ni) {
      const int gcol = jb * BM + wx * 64 + ni * 16 + fr;
      #pragma unroll
      for (int r = 0; r < 4; ++r) {
        const int grow = ib * BM + wy * 64 + mi * 16 + g * 4 + r;
        const float dot = acc[mi][ni][r];
        const float e = (gcol == grow) ? 0.f : __expf((dot - 1.0f) * 10.0f);
        const float pos = (gcol == (grow ^ BHALF)) ? dot : 0.f;
        rsum[mi][r] += e;  prow[mi][r] += pos;
        csum[ni] += e;     pcol[ni] += pos;
      }
    }
  }

  // row side: reduce over fr (lane bits 0..3)
  #pragma unroll
  for (int mi = 0; mi < 4; ++mi)
    #pragma unroll
    for (int r = 0; r < 4; ++r) {
      float a = rsum[mi][r], b = prow[mi][r];
      #pragma unroll
      for (int msk = 1; msk < 16; msk <<= 1) { a += __shfl_xor(a, msk); b += __shfl_xor(b, msk); }
      rsum[mi][r] = a; prow[mi][r] = b;
    }
  // col side: reduce over g (lane bits 4..5)
  #pragma unroll
  for (int ni = 0; ni < 4; ++ni) {
    float a = csum[ni], b = pcol[ni];
    a += __shfl_xor(a, 16); b += __shfl_xor(b, 16);
    a += __shfl_xor(a, 32); b += __shfl_xor(b, 32);
    csum[ni] = a; pcol[ni] = b;
  }

  // cross-wave combine via LDS (aliases tile buffer; safe after barrier)
  __syncthreads();
  float* sc = (float*)lds;  // rS[wx][128]@0, rP@256, cS[wy][128]@512, cP@768 (floats)
  if (fr == 0) {
    #pragma unroll
    for (int mi = 0; mi < 4; ++mi)
      #pragma unroll
      for (int r = 0; r < 4; ++r) {
        const int row = wy * 64 + mi * 16 + g * 4 + r;
        sc[wx * 128 + row]       = rsum[mi][r];
        sc[256 + wx * 128 + row] = prow[mi][r];
      }
  }
  if (g == 0) {
    #pragma unroll
    for (int ni = 0; ni < 4; ++ni) {
      const int col = wx * 64 + ni * 16 + fr;
      sc[512 + wy * 128 + col] = csum[ni];
      sc[768 + wy * 128 + col] = pcol[ni];
    }
  }
  __syncthreads();

  if (tid < 128) {                     // rows of block ib -> slot jb
    const int row = tid;
    const float s = sc[row] + sc[128 + row];
    const float p = sc[256 + row] + sc[384 + row];
    psum[(size_t)jb * NROW + ib * BM + row] = s;
    ppos[(size_t)jb * NROW + ib * BM + row] = p;
  } else if (ib != jb) {               // rows of block jb -> slot ib (transpose side)
    const int col = tid - 128;
    const float s = sc[512 + col] + sc[640 + col];
    const float p = sc[768 + col] + sc[896 + col];
    psum[(size_t)ib * NROW + jb * BM + col] = s;
    ppos[(size_t)ib * NROW + jb * BM + col] = p;
  }
}

// ---------------- Kernel 3a: per-row loss, 64 partials ----------------
__global__ __launch_bounds__(128) void loss_stage1(const float* __restrict__ psum,
                                                   const float* __restrict__ ppos,
                                                   float* __restrict__ partial) {
  const int row = blockIdx.x * 128 + threadIdx.x;
  float s = 0.f, p = 0.f;
  #pragma unroll 8
  for (int sl = 0; sl < NB; ++sl) {
    s += psum[(size_t)sl * NROW + row];
    p += ppos[(size_t)sl * NROW + row];
  }
  float local = logf(s) + 10.0f - 10.0f * p;
  #pragma unroll
  for (int m = 1; m < 64; m <<= 1) local += __shfl_xor(local, m);
  __shared__ float red[2];
  if ((threadIdx.x & 63) == 0) red[threadIdx.x >> 6] = local;
  __syncthreads();
  if (threadIdx.x == 0) partial[blockIdx.x] = red[0] + red[1];
}

// ---------------- Kernel 3b: final scalar ----------------
__global__ __launch_bounds__(64) void loss_stage2(const float* __restrict__ partial,
                                                  float* __restrict__ out) {
  float v = partial[threadIdx.x];
  #pragma unroll
  for (int m = 1; m < 64; m <<= 1) v += __shfl_xor(v, m);
  if (threadIdx.x == 0) out[0] = v * (1.0f / (float)BHALF);
}

extern "C" void kernel_launch(void* const* d_in, const int* in_sizes, int n_in,
                              void* d_out, int out_size, void* d_ws, size_t ws_size,
                              hipStream_t stream) {
  const float* feat = (const float*)d_in[0];
  char* ws = (char*)d_ws;
  __hip_bfloat16* f = (__hip_bfloat16*)ws;                         // 8 MB
  float* psum = (float*)(ws + (size_t)NROW * DIM * 2);             // NB*NROW floats (2 MB)
  float* ppos = psum + (size_t)NB * NROW;                          // 2 MB
  float* partial = ppos + (size_t)NB * NROW;                       // 64 floats
  float* out = (float*)d_out;

  normalize_kernel<<<NROW / 4, 256, 0, stream>>>(feat, f);
  pair_gram_kernel<<<NPAIR, 256, 0, stream>>>(f, psum, ppos);
  loss_stage1<<<NROW / 128, 128, 0, stream>>>(psum, ppos, partial);
  loss_stage2<<<1, 64, 0, stream>>>(partial, out);
}

// Round 11
// 61.015 us; speedup vs baseline: 2.5959x; 1.1743x over previous
//
#include <hip/hip_runtime.h>
#include <hip/hip_bf16.h>

typedef __attribute__((ext_vector_type(8))) short short8;
typedef __attribute__((ext_vector_type(4))) float f32x4;

#define NROW 8192
#define DIM 512
#define BHALF 4096
#define NB 64            // number of 128-row blocks
#define BM 128
#define BK 64            // 128-B LDS rows + XOR swizzle -> measured 0 bank conflicts
#define NPAIR 2080       // NB*(NB+1)/2
#define XCHUNK 260       // 2080/8

__device__ __forceinline__ void gload_lds16(const void* g, void* l) {
  __builtin_amdgcn_global_load_lds(
      (const __attribute__((address_space(1))) void*)g,
      (__attribute__((address_space(3))) void*)l,
      16, 0, 0);
}

// DPP 16-lane sum (row_ror 8/4/2/1): VALU pipe, no LDS traffic.
template <int CTRL>
__device__ __forceinline__ float dpp_ror_add(float v) {
  const int r = __builtin_amdgcn_update_dpp(0, __float_as_int(v), CTRL, 0xf, 0xf, false);
  return v + __int_as_float(r);
}
__device__ __forceinline__ float sum16_dpp(float v) {
  v = dpp_ror_add<0x128>(v);   // row_ror:8
  v = dpp_ror_add<0x124>(v);   // row_ror:4
  v = dpp_ror_add<0x122>(v);   // row_ror:2
  v = dpp_ror_add<0x121>(v);   // row_ror:1
  return v;                    // all 16 lanes hold the row-group sum
}

// ---------------- Kernel 1: row L2-normalize fp32 -> bf16 (wave per row) ----------------
__global__ __launch_bounds__(256) void normalize_kernel(const float* __restrict__ in,
                                                        __hip_bfloat16* __restrict__ out) {
  const int w = threadIdx.x >> 6, lane = threadIdx.x & 63;
  const int row = blockIdx.x * 4 + w;
  const float4* src = (const float4*)(in + (size_t)row * DIM) + lane * 2;
  const float4 v0 = src[0], v1 = src[1];
  float ss = v0.x * v0.x + v0.y * v0.y + v0.z * v0.z + v0.w * v0.w
           + v1.x * v1.x + v1.y * v1.y + v1.z * v1.z + v1.w * v1.w;
  #pragma unroll
  for (int m = 1; m < 64; m <<= 1) ss += __shfl_xor(ss, m);
  const float inv = 1.0f / fmaxf(sqrtf(ss), 1e-12f);
  __hip_bfloat16 o[8];
  o[0] = __float2bfloat16(v0.x * inv); o[1] = __float2bfloat16(v0.y * inv);
  o[2] = __float2bfloat16(v0.z * inv); o[3] = __float2bfloat16(v0.w * inv);
  o[4] = __float2bfloat16(v1.x * inv); o[5] = __float2bfloat16(v1.y * inv);
  o[6] = __float2bfloat16(v1.z * inv); o[7] = __float2bfloat16(v1.w * inv);
  *(short8*)(out + (size_t)row * DIM + lane * 8) = *(const short8*)o;
}

// ---------------- Kernel 2: symmetric 128x128 pair-tile Gram + exp-sums ----------------
// r7/r10 K-loop (best measured): 2080 blocks (ib<=jb pairs), 256 threads =
// 4 waves (2x2), 4x4 frags of 16x16x32, BK=64, single-buffer 32 KB LDS,
// 2-barrier loop, XOR swizzle (0 conflicts), launch_bounds(256,4).
// NEW epilogue: (1) 16-lane reductions via DPP row_ror (VALU, off the LDS
// pipe); (2) positive-pair extracted by direct LDS scatter only in the 32
// blocks with jb==ib+32 (tile diagonal, one element per row) -- no prow/pcol
// accumulate+shuffle anywhere.
__global__ __launch_bounds__(256, 4) void pair_gram_kernel(const __hip_bfloat16* __restrict__ f,
                                                           float* __restrict__ psum,
                                                           float* __restrict__ ppos) {
  __shared__ __align__(16) char lds[32768];   // A[128][64] @0, B[128][64] @16384

  // --- XCD swizzle + 16x16 macro-tiled triangular pair decode (scalar-uniform) ---
  const int bid = blockIdx.x;
  const int wg = (bid & 7) * XCHUNK + (bid >> 3);
  int rem = wg, MI = 0, MJ = 0;
  {
    bool brk = false;
    for (MI = 0; MI < 4 && !brk; ++MI) {
      for (MJ = MI; MJ < 4; ++MJ) {
        const int sz = (MI == MJ) ? 136 : 256;
        if (rem < sz) { brk = true; break; }
        rem -= sz;
      }
    }
    if (brk) --MI;
  }
  int ib, jb;
  if (MI == MJ) {          // 16x16 triangle: 136 entries
    int i = 0, b = 0;
    while (b + (16 - i) <= rem) { b += 16 - i; ++i; }
    ib = MI * 16 + i; jb = MI * 16 + i + (rem - b);
  } else {
    ib = MI * 16 + (rem >> 4); jb = MJ * 16 + (rem & 15);
  }
  const bool has_pos = (jb == ib + 32);   // pos-pair tiles: gcol == grow ^ 4096

  const int tid = threadIdx.x;
  const int lane = tid & 63;
  const int w = tid >> 6;            // wave 0..3
  const int wy = w >> 1;             // row half (0/1): rows wy*64..+64
  const int wx = w & 1;              // col half (0/1): cols wx*64..+64
  const int fr = lane & 15;          // fragment row/col index
  const int g = lane >> 4;           // k-group / C-row group

  // staging source (inverse-swizzled): lane covers row w*8+(lane>>3) (+q*32),
  // global col16 (lane&7)^((lane>>3)&7); LDS dest linear (base + lane*16).
  const int srow8 = lane >> 3;
  const int scol = (lane & 7) ^ srow8;
  const __hip_bfloat16* gA = f + (size_t)(ib * BM + w * 8 + srow8) * DIM + scol * 8;
  const __hip_bfloat16* gB = f + (size_t)(jb * BM + w * 8 + srow8) * DIM + scol * 8;
  char* dA = lds + w * 1024;          // + q*4096
  char* dB = lds + 16384 + w * 1024;  // + q*4096

  f32x4 acc[4][4];
  const f32x4 zero = {0.f, 0.f, 0.f, 0.f};
  #pragma unroll
  for (int mi = 0; mi < 4; ++mi)
    #pragma unroll
    for (int ni = 0; ni < 4; ++ni) acc[mi][ni] = zero;

  // read-side swizzled 16B-slot offsets: sk(kk) = ((kk*4+g) ^ (fr&7)) * 16
  const int f7 = fr & 7;
  const int sk0 = ((0 + g) ^ f7) * 16;
  const int sk1 = ((4 + g) ^ f7) * 16;
  const int arow = (wy * 64 + fr) * 128;          // + mi*16*128
  const int brow = 16384 + (wx * 64 + fr) * 128;  // + ni*16*128

  for (int t = 0; t < 8; ++t) {
    __syncthreads();                  // previous tile's ds_reads complete
    const int k0 = t * BK;
    #pragma unroll
    for (int q = 0; q < 4; ++q) {
      gload_lds16(gA + k0 + (size_t)q * 32 * DIM, dA + q * 4096);
      gload_lds16(gB + k0 + (size_t)q * 32 * DIM, dB + q * 4096);
    }
    __syncthreads();                  // vmcnt(0) drain: tile staged

    #pragma unroll
    for (int kk = 0; kk < 2; ++kk) {
      const int sk = kk ? sk1 : sk0;
      short8 aF[4], bF[4];
      #pragma unroll
      for (int mi = 0; mi < 4; ++mi) aF[mi] = *(const short8*)(lds + arow + mi * 2048 + sk);
      #pragma unroll
      for (int ni = 0; ni < 4; ++ni) bF[ni] = *(const short8*)(lds + brow + ni * 2048 + sk);
      __builtin_amdgcn_s_setprio(1);
      #pragma unroll
      for (int mi = 0; mi < 4; ++mi)
        #pragma unroll
        for (int ni = 0; ni < 4; ++ni)
          acc[mi][ni] = __builtin_amdgcn_mfma_f32_16x16x32_bf16(aF[mi], bF[ni], acc[mi][ni], 0, 0, 0);
      __builtin_amdgcn_s_setprio(0);
    }
  }

  // ---- epilogue: exp, row-sums (rows of ib) + col-sums (rows of jb) ----
  const bool isdiag = (ib == jb);
  float rsum[4][4], csum[4];
  #pragma unroll
  for (int mi = 0; mi < 4; ++mi)
    #pragma unroll
    for (int r = 0; r < 4; ++r) rsum[mi][r] = 0.f;
  #pragma unroll
  for (int ni = 0; ni < 4; ++ni) csum[ni] = 0.f;

  #pragma unroll
  for (int mi = 0; mi < 4; ++mi) {
    #pragma unroll
    for (int ni = 0; ni < 4; ++ni) {
      const int lc = wx * 64 + ni * 16 + fr;
      #pragma unroll
      for (int r = 0; r < 4; ++r) {
        const int lr = wy * 64 + mi * 16 + g * 4 + r;
        const float dot = acc[mi][ni][r];
        const float e = (isdiag && lc == lr) ? 0.f : __expf((dot - 1.0f) * 10.0f);
        rsum[mi][r] += e;
        csum[ni] += e;
      }
    }
  }

  // row side: 16-lane DPP reduce (VALU pipe)
  #pragma unroll
  for (int mi = 0; mi < 4; ++mi)
    #pragma unroll
    for (int r = 0; r < 4; ++r) rsum[mi][r] = sum16_dpp(rsum[mi][r]);
  // col side: reduce over g (lane bits 4..5) -- 8 shuffles total
  #pragma unroll
  for (int ni = 0; ni < 4; ++ni) {
    float a = csum[ni];
    a += __shfl_xor(a, 16);
    a += __shfl_xor(a, 32);
    csum[ni] = a;
  }

  // cross-wave combine via LDS (aliases tile buffer; safe after barrier)
  __syncthreads();
  float* sc = (float*)lds;  // rS[wx][128]@0, cS[wy][128]@256, pos[128]@512 (floats)
  if (fr == 0) {
    #pragma unroll
    for (int mi = 0; mi < 4; ++mi)
      #pragma unroll
      for (int r = 0; r < 4; ++r) {
        const int row = wy * 64 + mi * 16 + g * 4 + r;
        sc[wx * 128 + row] = rsum[mi][r];
      }
  }
  if (g == 0) {
    #pragma unroll
    for (int ni = 0; ni < 4; ++ni) {
      const int col = wx * 64 + ni * 16 + fr;
      sc[256 + wy * 128 + col] = csum[ni];
    }
  }
  if (has_pos && wy == wx) {
    // pos-pair = tile diagonal; exactly one element per local row lr.
    #pragma unroll
    for (int mi = 0; mi < 4; ++mi)
      #pragma unroll
      for (int r = 0; r < 4; ++r)
        if (fr == g * 4 + r) {   // lc == lr within this (wy==wx) wave, ni==mi
          const int lr = wy * 64 + mi * 16 + g * 4 + r;
          sc[512 + lr] = acc[mi][mi][r];
        }
  }
  __syncthreads();

  if (tid < 128) {                     // rows of block ib -> slot jb
    const int row = tid;
    const float s = sc[row] + sc[128 + row];
    const float p = has_pos ? sc[512 + row] : 0.f;
    psum[(size_t)jb * NROW + ib * BM + row] = s;
    ppos[(size_t)jb * NROW + ib * BM + row] = p;
  } else if (ib != jb) {               // rows of block jb -> slot ib (transpose side)
    const int col = tid - 128;
    const float s = sc[256 + col] + sc[384 + col];
    const float p = has_pos ? sc[512 + col] : 0.f;
    psum[(size_t)ib * NROW + jb * BM + col] = s;
    ppos[(size_t)ib * NROW + jb * BM + col] = p;
  }
}

// ---------------- Kernel 3a: per-row loss, 64 partials ----------------
__global__ __launch_bounds__(128) void loss_stage1(const float* __restrict__ psum,
                                                   const float* __restrict__ ppos,
                                                   float* __restrict__ partial) {
  const int row = blockIdx.x * 128 + threadIdx.x;
  float s = 0.f, p = 0.f;
  #pragma unroll 8
  for (int sl = 0; sl < NB; ++sl) {
    s += psum[(size_t)sl * NROW + row];
    p += ppos[(size_t)sl * NROW + row];
  }
  float local = logf(s) + 10.0f - 10.0f * p;
  #pragma unroll
  for (int m = 1; m < 64; m <<= 1) local += __shfl_xor(local, m);
  __shared__ float red[2];
  if ((threadIdx.x & 63) == 0) red[threadIdx.x >> 6] = local;
  __syncthreads();
  if (threadIdx.x == 0) partial[blockIdx.x] = red[0] + red[1];
}

// ---------------- Kernel 3b: final scalar ----------------
__global__ __launch_bounds__(64) void loss_stage2(const float* __restrict__ partial,
                                                  float* __restrict__ out) {
  float v = partial[threadIdx.x];
  #pragma unroll
  for (int m = 1; m < 64; m <<= 1) v += __shfl_xor(v, m);
  if (threadIdx.x == 0) out[0] = v * (1.0f / (float)BHALF);
}

extern "C" void kernel_launch(void* const* d_in, const int* in_sizes, int n_in,
                              void* d_out, int out_size, void* d_ws, size_t ws_size,
                              hipStream_t stream) {
  const float* feat = (const float*)d_in[0];
  char* ws = (char*)d_ws;
  __hip_bfloat16* f = (__hip_bfloat16*)ws;                         // 8 MB
  float* psum = (float*)(ws + (size_t)NROW * DIM * 2);             // NB*NROW floats (2 MB)
  float* ppos = psum + (size_t)NB * NROW;                          // 2 MB
  float* partial = ppos + (size_t)NB * NROW;                       // 64 floats
  float* out = (float*)d_out;

  normalize_kernel<<<NROW / 4, 256, 0, stream>>>(feat, f);
  pair_gram_kernel<<<NPAIR, 256, 0, stream>>>(f, psum, ppos);
  loss_stage1<<<NROW / 128, 128, 0, stream>>>(psum, ppos, partial);
  loss_stage2<<<1, 64, 0, stream>>>(partial, out);
}

// Round 12
// 46.874 us; speedup vs baseline: 3.3790x; 1.3017x over previous
//
#include <hip/hip_runtime.h>
#include <hip/hip_bf16.h>

typedef __attribute__((ext_vector_type(4))) int i32x4;

#define NROW 8192
#define DIM 512          // elements per row; i8 row = 512 bytes
#define BHALF 4096
#define NB 64            // number of 128-row blocks
#define BM 128
#define NPAIR 2080       // NB*(NB+1)/2
#define XCHUNK 260       // 2080/8

__device__ __forceinline__ void gload_lds16(const void* g, void* l) {
  __builtin_amdgcn_global_load_lds(
      (const __attribute__((address_space(1))) void*)g,
      (__attribute__((address_space(3))) void*)l,
      16, 0, 0);
}

// DPP 16-lane sum (row_ror 8/4/2/1): VALU pipe, no LDS traffic.
template <int CTRL>
__device__ __forceinline__ float dpp_ror_add(float v) {
  const int r = __builtin_amdgcn_update_dpp(0, __float_as_int(v), CTRL, 0xf, 0xf, false);
  return v + __int_as_float(r);
}
__device__ __forceinline__ float sum16_dpp(float v) {
  v = dpp_ror_add<0x128>(v);   // row_ror:8
  v = dpp_ror_add<0x124>(v);   // row_ror:4
  v = dpp_ror_add<0x122>(v);   // row_ror:2
  v = dpp_ror_add<0x121>(v);   // row_ror:1
  return v;
}

// ---------------- Kernel 1: row L2-normalize fp32 -> int8 (wave per row) ----------------
// q = rint(127 * v / ||v||), clamped to [-127,127]. Per-lane: 8 floats in, 8 i8 out.
__global__ __launch_bounds__(256) void normalize_kernel(const float* __restrict__ in,
                                                        signed char* __restrict__ out) {
  const int w = threadIdx.x >> 6, lane = threadIdx.x & 63;
  const int row = blockIdx.x * 4 + w;
  const float4* src = (const float4*)(in + (size_t)row * DIM) + lane * 2;
  const float4 v0 = src[0], v1 = src[1];
  float ss = v0.x * v0.x + v0.y * v0.y + v0.z * v0.z + v0.w * v0.w
           + v1.x * v1.x + v1.y * v1.y + v1.z * v1.z + v1.w * v1.w;
  #pragma unroll
  for (int m = 1; m < 64; m <<= 1) ss += __shfl_xor(ss, m);
  const float s127 = 127.0f / fmaxf(sqrtf(ss), 1e-12f);
  float vv[8] = {v0.x, v0.y, v0.z, v0.w, v1.x, v1.y, v1.z, v1.w};
  signed char q[8];
  #pragma unroll
  for (int j = 0; j < 8; ++j) {
    int qi = __float2int_rn(vv[j] * s127);
    qi = qi > 127 ? 127 : (qi < -127 ? -127 : qi);
    q[j] = (signed char)qi;
  }
  *(int2*)(out + (size_t)row * 512 + lane * 8) = *(const int2*)q;
}

// ---------------- Kernel 2: symmetric 128x128 pair-tile Gram (int8 MFMA) + exp-sums ----------------
// r11 structure with i8: 2080 blocks (ib<=jb pairs), 256 threads = 4 waves (2x2),
// 4x4 frags of 16x16x64 i8. Rows of 128 B (BK=128 i8), 4 K-tiles, 2 k-slots each.
// XOR swizzle & staging lane-map byte-identical to the proven bf16 kernel
// (0 bank conflicts). Single-buffer 32 KB LDS, 2-barrier loop, lb(256,4).
// Epilogue: DPP row-reduce (VALU) + direct pos-pair scatter (jb==ib+32 only).
__global__ __launch_bounds__(256, 4) void pair_gram_kernel(const signed char* __restrict__ f8,
                                                           float* __restrict__ psum,
                                                           float* __restrict__ ppos) {
  __shared__ __align__(16) char lds[32768];   // A[128][128B] @0, B[128][128B] @16384

  // --- XCD swizzle + 16x16 macro-tiled triangular pair decode (scalar-uniform) ---
  const int bid = blockIdx.x;
  const int wg = (bid & 7) * XCHUNK + (bid >> 3);
  int rem = wg, MI = 0, MJ = 0;
  {
    bool brk = false;
    for (MI = 0; MI < 4 && !brk; ++MI) {
      for (MJ = MI; MJ < 4; ++MJ) {
        const int sz = (MI == MJ) ? 136 : 256;
        if (rem < sz) { brk = true; break; }
        rem -= sz;
      }
    }
    if (brk) --MI;
  }
  int ib, jb;
  if (MI == MJ) {          // 16x16 triangle: 136 entries
    int i = 0, b = 0;
    while (b + (16 - i) <= rem) { b += 16 - i; ++i; }
    ib = MI * 16 + i; jb = MI * 16 + i + (rem - b);
  } else {
    ib = MI * 16 + (rem >> 4); jb = MJ * 16 + (rem & 15);
  }
  const bool has_pos = (jb == ib + 32);   // pos-pair tiles: gcol == grow ^ 4096

  const int tid = threadIdx.x;
  const int lane = tid & 63;
  const int w = tid >> 6;            // wave 0..3
  const int wy = w >> 1;             // row half (0/1)
  const int wx = w & 1;              // col half (0/1)
  const int fr = lane & 15;          // fragment row/col index
  const int g = lane >> 4;           // k-group

  // staging source (inverse-swizzled): lane covers row w*8+(lane>>3) (+q*32),
  // global 16B-chunk (lane&7)^((lane>>3)&7); LDS dest linear (base + lane*16).
  const int srow8 = lane >> 3;
  const int scol = (lane & 7) ^ srow8;
  const signed char* gA = f8 + (size_t)(ib * BM + w * 8 + srow8) * 512 + scol * 16;
  const signed char* gB = f8 + (size_t)(jb * BM + w * 8 + srow8) * 512 + scol * 16;
  char* dA = lds + w * 1024;          // + q*4096
  char* dB = lds + 16384 + w * 1024;  // + q*4096

  i32x4 acc[4][4];
  const i32x4 izero = {0, 0, 0, 0};
  #pragma unroll
  for (int mi = 0; mi < 4; ++mi)
    #pragma unroll
    for (int ni = 0; ni < 4; ++ni) acc[mi][ni] = izero;

  // fragment reads: row r at byte r*128; k-slot (ks*4+g), XOR-swizzled by (fr&7)
  const int f7 = fr & 7;
  const int sk0 = ((0 + g) ^ f7) * 16;   // ks=0
  const int sk1 = ((4 + g) ^ f7) * 16;   // ks=1
  const int arow = (wy * 64 + fr) * 128;          // + mi*16*128
  const int brow = 16384 + (wx * 64 + fr) * 128;  // + ni*16*128

  for (int t = 0; t < 4; ++t) {
    __syncthreads();                  // previous tile's ds_reads complete
    const int k0 = t * 128;           // byte offset in row (BK=128 i8)
    #pragma unroll
    for (int q = 0; q < 4; ++q) {
      gload_lds16(gA + k0 + (size_t)q * 32 * 512, dA + q * 4096);
      gload_lds16(gB + k0 + (size_t)q * 32 * 512, dB + q * 4096);
    }
    __syncthreads();                  // staging complete

    #pragma unroll
    for (int ks = 0; ks < 2; ++ks) {
      const int sk = ks ? sk1 : sk0;
      i32x4 aF[4], bF[4];
      #pragma unroll
      for (int mi = 0; mi < 4; ++mi) aF[mi] = *(const i32x4*)(lds + arow + mi * 2048 + sk);
      #pragma unroll
      for (int ni = 0; ni < 4; ++ni) bF[ni] = *(const i32x4*)(lds + brow + ni * 2048 + sk);
      __builtin_amdgcn_s_setprio(1);
      #pragma unroll
      for (int mi = 0; mi < 4; ++mi)
        #pragma unroll
        for (int ni = 0; ni < 4; ++ni)
          acc[mi][ni] = __builtin_amdgcn_mfma_i32_16x16x64_i8(aF[mi], bF[ni], acc[mi][ni], 0, 0, 0);
      __builtin_amdgcn_s_setprio(0);
    }
  }

  // ---- epilogue: exp, row-sums + col-sums; logit*10 = acc * (10/127^2) ----
  const float SC10 = 10.0f / 16129.0f;
  const bool isdiag = (ib == jb);
  float rsum[4][4], csum[4];
  #pragma unroll
  for (int mi = 0; mi < 4; ++mi)
    #pragma unroll
    for (int r = 0; r < 4; ++r) rsum[mi][r] = 0.f;
  #pragma unroll
  for (int ni = 0; ni < 4; ++ni) csum[ni] = 0.f;

  #pragma unroll
  for (int mi = 0; mi < 4; ++mi) {
    #pragma unroll
    for (int ni = 0; ni < 4; ++ni) {
      const int lc = wx * 64 + ni * 16 + fr;
      #pragma unroll
      for (int r = 0; r < 4; ++r) {
        const int lr = wy * 64 + mi * 16 + g * 4 + r;
        const float l10 = (float)acc[mi][ni][r] * SC10;
        const float e = (isdiag && lc == lr) ? 0.f : __expf(l10 - 10.0f);
        rsum[mi][r] += e;
        csum[ni] += e;
      }
    }
  }

  // row side: 16-lane DPP reduce (VALU pipe)
  #pragma unroll
  for (int mi = 0; mi < 4; ++mi)
    #pragma unroll
    for (int r = 0; r < 4; ++r) rsum[mi][r] = sum16_dpp(rsum[mi][r]);
  // col side: reduce over g (lane bits 4..5)
  #pragma unroll
  for (int ni = 0; ni < 4; ++ni) {
    float a = csum[ni];
    a += __shfl_xor(a, 16);
    a += __shfl_xor(a, 32);
    csum[ni] = a;
  }

  // cross-wave combine via LDS (aliases tile buffer; safe after barrier)
  __syncthreads();
  float* sc = (float*)lds;  // rS[wx][128]@0, cS[wy][128]@256, pos[128]@512 (floats)
  if (fr == 0) {
    #pragma unroll
    for (int mi = 0; mi < 4; ++mi)
      #pragma unroll
      for (int r = 0; r < 4; ++r) {
        const int row = wy * 64 + mi * 16 + g * 4 + r;
        sc[wx * 128 + row] = rsum[mi][r];
      }
  }
  if (g == 0) {
    #pragma unroll
    for (int ni = 0; ni < 4; ++ni) {
      const int col = wx * 64 + ni * 16 + fr;
      sc[256 + wy * 128 + col] = csum[ni];
    }
  }
  if (has_pos && wy == wx) {
    // pos-pair = tile diagonal; exactly one element per local row.
    #pragma unroll
    for (int mi = 0; mi < 4; ++mi)
      #pragma unroll
      for (int r = 0; r < 4; ++r)
        if (fr == g * 4 + r) {
          const int lr = wy * 64 + mi * 16 + g * 4 + r;
          sc[512 + lr] = (float)acc[mi][mi][r] * (1.0f / 16129.0f);
        }
  }
  __syncthreads();

  if (tid < 128) {                     // rows of block ib -> slot jb
    const int row = tid;
    const float s = sc[row] + sc[128 + row];
    const float p = has_pos ? sc[512 + row] : 0.f;
    psum[(size_t)jb * NROW + ib * BM + row] = s;
    ppos[(size_t)jb * NROW + ib * BM + row] = p;
  } else if (ib != jb) {               // rows of block jb -> slot ib (transpose side)
    const int col = tid - 128;
    const float s = sc[256 + col] + sc[384 + col];
    const float p = has_pos ? sc[512 + col] : 0.f;
    psum[(size_t)ib * NROW + jb * BM + col] = s;
    ppos[(size_t)ib * NROW + jb * BM + col] = p;
  }
}

// ---------------- Kernel 3a: per-row loss, 64 partials ----------------
__global__ __launch_bounds__(128) void loss_stage1(const float* __restrict__ psum,
                                                   const float* __restrict__ ppos,
                                                   float* __restrict__ partial) {
  const int row = blockIdx.x * 128 + threadIdx.x;
  float s = 0.f, p = 0.f;
  #pragma unroll 8
  for (int sl = 0; sl < NB; ++sl) {
    s += psum[(size_t)sl * NROW + row];
    p += ppos[(size_t)sl * NROW + row];
  }
  float local = logf(s) + 10.0f - 10.0f * p;
  #pragma unroll
  for (int m = 1; m < 64; m <<= 1) local += __shfl_xor(local, m);
  __shared__ float red[2];
  if ((threadIdx.x & 63) == 0) red[threadIdx.x >> 6] = local;
  __syncthreads();
  if (threadIdx.x == 0) partial[blockIdx.x] = red[0] + red[1];
}

// ---------------- Kernel 3b: final scalar ----------------
__global__ __launch_bounds__(64) void loss_stage2(const float* __restrict__ partial,
                                                  float* __restrict__ out) {
  float v = partial[threadIdx.x];
  #pragma unroll
  for (int m = 1; m < 64; m <<= 1) v += __shfl_xor(v, m);
  if (threadIdx.x == 0) out[0] = v * (1.0f / (float)BHALF);
}

extern "C" void kernel_launch(void* const* d_in, const int* in_sizes, int n_in,
                              void* d_out, int out_size, void* d_ws, size_t ws_size,
                              hipStream_t stream) {
  const float* feat = (const float*)d_in[0];
  char* ws = (char*)d_ws;
  signed char* f8 = (signed char*)ws;                              // 4 MB
  float* psum = (float*)(ws + (size_t)NROW * 512);                 // NB*NROW floats (2 MB)
  float* ppos = psum + (size_t)NB * NROW;                          // 2 MB
  float* partial = ppos + (size_t)NB * NROW;                       // 64 floats
  float* out = (float*)d_out;

  normalize_kernel<<<NROW / 4, 256, 0, stream>>>(feat, f8);
  pair_gram_kernel<<<NPAIR, 256, 0, stream>>>(f8, psum, ppos);
  loss_stage1<<<NROW / 128, 128, 0, stream>>>(psum, ppos, partial);
  loss_stage2<<<1, 64, 0, stream>>>(partial, out);
}